// Round 4
// baseline (34.801 us; speedup 1.0000x reference)
//
#include <hip/hip_runtime.h>
#include <stdint.h>

#define BB 16
#define CI 64
#define CO 64
#define HH 32
#define WW 32

// Pack sign bits of x: bit = (x > 0). One 32-bit word per (b,ci,y) row.
__global__ void pack_x_kernel(const float* __restrict__ x, uint32_t* __restrict__ xbits) {
    int p = blockIdx.x * blockDim.x + threadIdx.x;   // 0 .. B*CI*H*W-1
    bool bit = x[p] > 0.0f;
    unsigned long long mask = __ballot(bit);
    int lane = threadIdx.x & 63;
    if ((lane & 31) == 0) {
        uint32_t word = (lane == 32) ? (uint32_t)(mask >> 32) : (uint32_t)mask;
        xbits[p >> 5] = word;   // p>>5 == (b*CI+ci)*H + y
    }
}

// Pack 9 weight sign bits per (co,ci), stored transposed as [ci][co] for LDS reuse.
__global__ void pack_w_kernel(const float* __restrict__ w, uint32_t* __restrict__ wpack) {
    int idx = blockIdx.x * blockDim.x + threadIdx.x; // 0..4095
    int ci = idx >> 6, co = idx & 63;
    uint32_t bits = 0;
#pragma unroll
    for (int t = 0; t < 9; ++t) {
        float v = w[(co * 9 + t) * CI + ci];   // w[co][dy][dx][ci], t = dy*3+dx
        bits |= (v > 0.0f ? 1u : 0u) << t;
    }
    wpack[idx] = bits;   // [ci][co]
}

// Main: one block per (b,y); threads = (x=32, cog=8); each thread does 8 co, loops 64 ci.
__global__ __launch_bounds__(256) void majconv_kernel(const uint32_t* __restrict__ xbits,
                                                      const uint32_t* __restrict__ wpack,
                                                      float* __restrict__ out) {
    __shared__ uint32_t wlds[CI * CO];   // [ci][co], 16 KiB
    __shared__ uint32_t xr[3][CI];       // rows y-1, y, y+1 for all ci

    const int b = blockIdx.x >> 5;
    const int y = blockIdx.x & 31;
    const int x = threadIdx.x;           // 0..31
    const int cog = threadIdx.y;         // 0..7
    const int tid = cog * 32 + x;

    for (int i = tid; i < CI * CO; i += 256) wlds[i] = wpack[i];
    for (int i = tid; i < 3 * CI; i += 256) {
        int r = i >> 6, ci = i & 63;
        int yy = y - 1 + r;
        xr[r][ci] = (yy >= 0 && yy < HH) ? xbits[(b * CI + ci) * HH + yy] : 0u;
    }
    __syncthreads();

    // Valid-tap mask (bit t = dy*3+dx): tap valid iff source pixel in bounds.
    const uint32_t rowm = (x > 0 ? 1u : 0u) | 2u | (x < WW - 1 ? 4u : 0u);
    const uint32_t vmask = (y > 0 ? rowm : 0u) | (rowm << 3) | (y < HH - 1 ? (rowm << 6) : 0u);
    const int N = __popc(vmask);

    int acc[8] = {0, 0, 0, 0, 0, 0, 0, 0};
    for (int ci = 0; ci < CI; ++ci) {
        // Extract 3-bit neighborhoods (cols x-1,x,x+1) from each of 3 rows.
        uint64_t s0 = ((uint64_t)xr[0][ci]) << 1;
        uint64_t s1 = ((uint64_t)xr[1][ci]) << 1;
        uint64_t s2 = ((uint64_t)xr[2][ci]) << 1;
        uint32_t t0 = (uint32_t)(s0 >> x) & 7u;
        uint32_t t1 = (uint32_t)(s1 >> x) & 7u;
        uint32_t t2 = (uint32_t)(s2 >> x) & 7u;
        uint32_t xn = t0 | (t1 << 3) | (t2 << 6);
        const uint32_t* wrow = &wlds[ci * CO + cog * 8];
#pragma unroll
        for (int j = 0; j < 8; ++j) {
            uint32_t wn = wrow[j];
            int m = __popc((~(xn ^ wn)) & vmask);   // matches among valid taps
            int s = 2 * m - N;                      // s = matches - mismatches
            acc[j] += (s > 0) - (s < 0);            // sign(s)
        }
    }

#pragma unroll
    for (int j = 0; j < 8; ++j) {
        int co = cog * 8 + j;
        out[((b * CO + co) * HH + y) * WW + x] = (float)acc[j];
    }
}

extern "C" void kernel_launch(void* const* d_in, const int* in_sizes, int n_in,
                              void* d_out, int out_size, void* d_ws, size_t ws_size,
                              hipStream_t stream) {
    const float* x = (const float*)d_in[0];
    const float* w = (const float*)d_in[1];
    float* out = (float*)d_out;

    uint32_t* xbits = (uint32_t*)d_ws;           // B*CI*H words = 128 KiB
    uint32_t* wpack = xbits + BB * CI * HH;      // CI*CO words = 16 KiB

    pack_x_kernel<<<(BB * CI * HH * WW) / 256, 256, 0, stream>>>(x, xbits);
    pack_w_kernel<<<(CO * CI) / 256, 256, 0, stream>>>(w, wpack);

    dim3 blk(WW, 8);
    majconv_kernel<<<BB * HH, blk, 0, stream>>>(xbits, wpack, out);
}

// Round 5
// 31.739 us; speedup vs baseline: 1.0965x; 1.0965x over previous
//
#include <hip/hip_runtime.h>
#include <stdint.h>

#define BB 16
#define CI 64
#define CO 64
#define HH 32
#define WW 32

// One fused kernel: block = (b, y). Packs w-signs (inverted) and 3 x-rows into
// LDS, then computes majority conv for 32 pixels x 64 co.
__global__ __launch_bounds__(256) void fused_majconv(const float* __restrict__ x,
                                                     const float* __restrict__ w,
                                                     float* __restrict__ out) {
    __shared__ uint32_t wlds[CI * CO];   // [ci][co], 16 KiB; stores (wn ^ 0x1FF)
    __shared__ uint32_t xr[3][CI];       // rows y-1, y, y+1, bit per pixel

    const int b = blockIdx.x >> 5;
    const int y = blockIdx.x & 31;
    const int xpix = threadIdx.x;        // 0..31
    const int cog = threadIdx.y;         // 0..7
    const int tid = cog * 32 + xpix;

    // ---- pack weights: 1024 ci-quads; thread handles 4 quads.
    // quad q: co = q>>4, ci = (q&15)*4 .. +3. float4 over ci is coalesced.
    for (int q = tid; q < (CI / 4) * CO; q += 256) {
        int co = q >> 4;
        int ci0 = (q & 15) * 4;
        uint32_t b0 = 0, b1 = 0, b2 = 0, b3 = 0;
#pragma unroll
        for (int t = 0; t < 9; ++t) {
            const float4 v = *(const float4*)&w[(co * 9 + t) * CI + ci0];
            b0 |= (v.x > 0.f ? 1u : 0u) << t;
            b1 |= (v.y > 0.f ? 1u : 0u) << t;
            b2 |= (v.z > 0.f ? 1u : 0u) << t;
            b3 |= (v.w > 0.f ? 1u : 0u) << t;
        }
        wlds[(ci0 + 0) * CO + co] = b0 ^ 0x1FFu;   // pre-invert 9 bits:
        wlds[(ci0 + 1) * CO + co] = b1 ^ 0x1FFu;   // matches = popc((xn^winv)&vmask)
        wlds[(ci0 + 2) * CO + co] = b2 ^ 0x1FFu;
        wlds[(ci0 + 3) * CO + co] = b3 ^ 0x1FFu;
    }

    // ---- pack x rows y-1..y+1 for all 64 ci via ballot.
    // 192 tasks (task = r*64+ci); wave handles 2 tasks/iter (lanes 0-31 / 32-63).
    {
        const int wave = tid >> 6;       // 0..3
        const int lane = tid & 63;
        const int half = lane >> 5;      // 0 or 1
        const int px = lane & 31;
#pragma unroll
        for (int j = 0; j < 24; ++j) {
            int task = wave * 48 + j * 2 + half;
            int r = task >> 6;           // 0..2
            int ci = task & 63;
            int yy = y - 1 + r;
            float v = (yy >= 0 && yy < HH) ? x[((b * CI + ci) * HH + yy) * WW + px] : 0.f;
            unsigned long long mask = __ballot(v > 0.f);
            if (px == 0) {
                xr[r][ci] = (uint32_t)(half ? (mask >> 32) : mask);
            }
        }
    }
    __syncthreads();

    // ---- majority core.
    // Valid-tap mask (bit t = dy*3+dx): tap valid iff source pixel in bounds.
    const uint32_t rowm = (xpix > 0 ? 1u : 0u) | 2u | (xpix < WW - 1 ? 4u : 0u);
    const uint32_t vmask = (y > 0 ? rowm : 0u) | (rowm << 3) | (y < HH - 1 ? (rowm << 6) : 0u);
    const uint32_t N = __popc(vmask);
    const uint32_t t1 = N >> 1;          // s>0  <=> m > t1
    const uint32_t t2 = (N - 1) >> 1;    // s<0  <=> !(m > t2)

    int c1[8] = {0, 0, 0, 0, 0, 0, 0, 0};
    int c2[8] = {0, 0, 0, 0, 0, 0, 0, 0};

    for (int ci = 0; ci < CI; ++ci) {
        // 3-bit neighborhoods (cols x-1,x,x+1) from each row; <<1 handles x=0.
        uint64_t s0 = ((uint64_t)xr[0][ci]) << 1;
        uint64_t s1 = ((uint64_t)xr[1][ci]) << 1;
        uint64_t s2 = ((uint64_t)xr[2][ci]) << 1;
        uint32_t t0v = (uint32_t)(s0 >> xpix) & 7u;
        uint32_t t1v = (uint32_t)(s1 >> xpix) & 7u;
        uint32_t t2v = (uint32_t)(s2 >> xpix) & 7u;
        uint32_t xn = t0v | (t1v << 3) | (t2v << 6);

        const uint4* wq = (const uint4*)&wlds[ci * CO + cog * 8];
        uint4 wa = wq[0];
        uint4 wb = wq[1];

        uint32_t m;
        m = (uint32_t)__popc((xn ^ wa.x) & vmask); c1[0] += (m > t1); c2[0] += (m > t2);
        m = (uint32_t)__popc((xn ^ wa.y) & vmask); c1[1] += (m > t1); c2[1] += (m > t2);
        m = (uint32_t)__popc((xn ^ wa.z) & vmask); c1[2] += (m > t1); c2[2] += (m > t2);
        m = (uint32_t)__popc((xn ^ wa.w) & vmask); c1[3] += (m > t1); c2[3] += (m > t2);
        m = (uint32_t)__popc((xn ^ wb.x) & vmask); c1[4] += (m > t1); c2[4] += (m > t2);
        m = (uint32_t)__popc((xn ^ wb.y) & vmask); c1[5] += (m > t1); c2[5] += (m > t2);
        m = (uint32_t)__popc((xn ^ wb.z) & vmask); c1[6] += (m > t1); c2[6] += (m > t2);
        m = (uint32_t)__popc((xn ^ wb.w) & vmask); c1[7] += (m > t1); c2[7] += (m > t2);
    }

#pragma unroll
    for (int j = 0; j < 8; ++j) {
        int co = cog * 8 + j;
        out[((b * CO + co) * HH + y) * WW + xpix] = (float)(c1[j] + c2[j] - CI);
    }
}

extern "C" void kernel_launch(void* const* d_in, const int* in_sizes, int n_in,
                              void* d_out, int out_size, void* d_ws, size_t ws_size,
                              hipStream_t stream) {
    const float* x = (const float*)d_in[0];
    const float* w = (const float*)d_in[1];
    float* out = (float*)d_out;

    dim3 blk(WW, 8);
    fused_majconv<<<BB * HH, blk, 0, stream>>>(x, w, out);
}

// Round 6
// 27.790 us; speedup vs baseline: 1.2523x; 1.1421x over previous
//
#include <hip/hip_runtime.h>
#include <stdint.h>

#define BB 16
#define CI 64
#define CO 64
#define HH 32
#define WW 32

// ws layout: xbits[BB*CI*HH] row bitmasks (64 KiB), then winv[CI*CO] (16 KiB).

// Grid = 4096 x-pack blocks + 16 w-pack blocks.
__global__ __launch_bounds__(256) void pack_kernel(const float* __restrict__ x,
                                                   const float* __restrict__ w,
                                                   uint32_t* __restrict__ xbits,
                                                   uint32_t* __restrict__ winv) {
    const int XBLK = (BB * CI * HH * WW) / 256;   // 4096
    int bid = blockIdx.x;
    if (bid < XBLK) {
        int p = bid * 256 + threadIdx.x;
        unsigned long long mask = __ballot(x[p] > 0.0f);
        int lane = threadIdx.x & 63;
        if ((lane & 31) == 0)
            xbits[p >> 5] = (lane & 32) ? (uint32_t)(mask >> 32) : (uint32_t)mask;
    } else {
        int idx = (bid - XBLK) * 256 + threadIdx.x;  // 0..4095
        int ci = idx & 63, co = idx >> 6;            // coalesced w loads over ci
        uint32_t bits = 0;
#pragma unroll
        for (int t = 0; t < 9; ++t)
            bits |= (w[(co * 9 + t) * CI + ci] > 0.f ? 1u : 0u) << t;
        winv[ci * CO + co] = bits ^ 0x1FFu;          // [ci][co], pre-inverted
    }
}

// Block = (b, y), 512 threads = 32 px * 8 cog * 2 ci-halves. 8 co per thread.
__global__ __launch_bounds__(512) void core_kernel(const uint32_t* __restrict__ xbits,
                                                   const uint32_t* __restrict__ winv,
                                                   float* __restrict__ out) {
    __shared__ uint32_t wlds[CI * CO];   // [ci][co], inverted; 16 KiB
    __shared__ uint4 xr4[CI];            // .x/.y/.z = rows y-1,y,y+1; 1 KiB
    __shared__ uint32_t red[8][32][2];   // byte-packed partial sums; 2 KiB

    const int b = blockIdx.x >> 5;
    const int y = blockIdx.x & 31;
    const int tid = threadIdx.x;
    const int px = tid & 31;
    const int cog = (tid >> 5) & 7;
    const int cih = tid >> 8;            // ci-half

    {   // stage winv -> LDS, fully coalesced (512 threads x 2 uint4)
        const uint4* src = (const uint4*)winv;
        uint4* dst = (uint4*)wlds;
        dst[tid * 2 + 0] = src[tid * 2 + 0];
        dst[tid * 2 + 1] = src[tid * 2 + 1];
    }
    if (tid < 3 * CI) {   // stage 3 x-rows for all ci
        int r = tid >> 6, ci = tid & 63;
        int yy = y - 1 + r;
        uint32_t v = (yy >= 0 && yy < HH) ? xbits[(b * CI + ci) * HH + yy] : 0u;
        ((uint32_t*)&xr4[ci])[r] = v;
    }
    __syncthreads();

    // Valid-tap mask and majority thresholds; LUT[m] = (m>t1)+(m>t2), 2 bits/m.
    const uint32_t rowm = (px > 0 ? 1u : 0u) | 2u | (px < WW - 1 ? 4u : 0u);
    const uint32_t vmask = (y > 0 ? rowm : 0u) | (rowm << 3) | (y < HH - 1 ? (rowm << 6) : 0u);
    const uint32_t N = __popc(vmask);
    const uint32_t t1 = N >> 1, t2 = (N - 1) >> 1;
    uint32_t lut = 0;
    for (uint32_t m = 1; m <= 9; ++m)
        lut |= (uint32_t)((m > t1) + (m > t2)) << (2 * m);

    uint32_t a0 = 0, a1 = 0, a2 = 0, a3 = 0, a4 = 0, a5 = 0, a6 = 0, a7 = 0;
    const int ci0 = cih * 32;
#pragma unroll 2
    for (int i = 0; i < 32; ++i) {
        const int ci = ci0 + i;
        const uint4 xrv = xr4[ci];
        const uint64_t s0 = ((uint64_t)xrv.x) << 1;
        const uint64_t s1 = ((uint64_t)xrv.y) << 1;
        const uint64_t s2 = ((uint64_t)xrv.z) << 1;
        const uint32_t n0 = (uint32_t)(s0 >> px) & 7u;
        const uint32_t n1 = (uint32_t)(s1 >> px) & 7u;
        const uint32_t n2 = (uint32_t)(s2 >> px) & 7u;
        const uint32_t xn = n0 | (n1 << 3) | (n2 << 6);
        const uint4* wq = (const uint4*)&wlds[ci * CO + cog * 8];
        const uint4 wa = wq[0], wb = wq[1];
        uint32_t m;
        m = (uint32_t)__popc((xn ^ wa.x) & vmask); a0 += (lut >> (2 * m)) & 3u;
        m = (uint32_t)__popc((xn ^ wa.y) & vmask); a1 += (lut >> (2 * m)) & 3u;
        m = (uint32_t)__popc((xn ^ wa.z) & vmask); a2 += (lut >> (2 * m)) & 3u;
        m = (uint32_t)__popc((xn ^ wa.w) & vmask); a3 += (lut >> (2 * m)) & 3u;
        m = (uint32_t)__popc((xn ^ wb.x) & vmask); a4 += (lut >> (2 * m)) & 3u;
        m = (uint32_t)__popc((xn ^ wb.y) & vmask); a5 += (lut >> (2 * m)) & 3u;
        m = (uint32_t)__popc((xn ^ wb.z) & vmask); a6 += (lut >> (2 * m)) & 3u;
        m = (uint32_t)__popc((xn ^ wb.w) & vmask); a7 += (lut >> (2 * m)) & 3u;
    }

    // Combine ci-halves: byte-packed (each acc <= 64, sum <= 128: no byte carry).
    const uint32_t w0 = a0 | (a1 << 8) | (a2 << 16) | (a3 << 24);
    const uint32_t w1 = a4 | (a5 << 8) | (a6 << 16) | (a7 << 24);
    if (cih == 1) {
        red[cog][px][0] = w0;
        red[cog][px][1] = w1;
    }
    __syncthreads();
    if (cih == 0) {
        const uint32_t s0w = red[cog][px][0] + w0;
        const uint32_t s1w = red[cog][px][1] + w1;
        float* op = &out[(((size_t)b * CO + cog * 8) * HH + y) * WW + px];
        op[0 * HH * WW] = (float)((int)(s0w & 0xFFu) - CI);
        op[1 * HH * WW] = (float)((int)((s0w >> 8) & 0xFFu) - CI);
        op[2 * HH * WW] = (float)((int)((s0w >> 16) & 0xFFu) - CI);
        op[3 * HH * WW] = (float)((int)((s0w >> 24) & 0xFFu) - CI);
        op[4 * HH * WW] = (float)((int)(s1w & 0xFFu) - CI);
        op[5 * HH * WW] = (float)((int)((s1w >> 8) & 0xFFu) - CI);
        op[6 * HH * WW] = (float)((int)((s1w >> 16) & 0xFFu) - CI);
        op[7 * HH * WW] = (float)((int)((s1w >> 24) & 0xFFu) - CI);
    }
}

extern "C" void kernel_launch(void* const* d_in, const int* in_sizes, int n_in,
                              void* d_out, int out_size, void* d_ws, size_t ws_size,
                              hipStream_t stream) {
    const float* x = (const float*)d_in[0];
    const float* w = (const float*)d_in[1];
    float* out = (float*)d_out;

    uint32_t* xbits = (uint32_t*)d_ws;          // 16384 words
    uint32_t* winv = xbits + BB * CI * HH;      // 4096 words

    const int XBLK = (BB * CI * HH * WW) / 256; // 4096
    pack_kernel<<<XBLK + 16, 256, 0, stream>>>(x, w, xbits, winv);
    core_kernel<<<BB * HH, 512, 0, stream>>>(xbits, winv, out);
}

// Round 7
// 21.917 us; speedup vs baseline: 1.5879x; 1.2680x over previous
//
#include <hip/hip_runtime.h>
#include <stdint.h>

#define BB 16
#define CI 64
#define CO 64
#define HH 32
#define WW 32

// ---------- pack: xbits row bitmasks + inverted 9-bit weight signs ----------
__global__ __launch_bounds__(256) void pack_kernel(const float* __restrict__ x,
                                                   const float* __restrict__ w,
                                                   uint32_t* __restrict__ xbits,
                                                   uint32_t* __restrict__ winv) {
    const int XBLK = (BB * CI * HH * WW) / 256;   // 4096
    int bid = blockIdx.x;
    if (bid < XBLK) {
        int p = bid * 256 + threadIdx.x;
        unsigned long long mask = __ballot(x[p] > 0.0f);
        int lane = threadIdx.x & 63;
        if ((lane & 31) == 0)
            xbits[p >> 5] = (lane & 32) ? (uint32_t)(mask >> 32) : (uint32_t)mask;
    } else {
        int idx = (bid - XBLK) * 256 + threadIdx.x;  // 0..4095
        int ci = idx & 63, co = idx >> 6;            // coalesced over ci
        uint32_t bits = 0;
#pragma unroll
        for (int t = 0; t < 9; ++t)
            bits |= (w[(co * 9 + t) * CI + ci] > 0.f ? 1u : 0u) << t;
        winv[ci * CO + co] = bits ^ 0x1FFu;          // [ci][co], inverted: match = xn ^ winv
    }
}

// full adder / half adder on 32-lane bitsets
__device__ __forceinline__ void fadd(uint32_t a, uint32_t b, uint32_t c,
                                     uint32_t& s, uint32_t& cy) {
    uint32_t t = a ^ b;
    s = t ^ c;
    cy = (t & c) | (a & b);
}
__device__ __forceinline__ void hadd(uint32_t a, uint32_t b, uint32_t& s, uint32_t& cy) {
    s = a ^ b;
    cy = a & b;
}
__device__ __forceinline__ void add5(const uint32_t* a, const uint32_t* b, uint32_t* r) {
    uint32_t c;
    hadd(a[0], b[0], r[0], c);
#pragma unroll
    for (int k = 1; k < 5; ++k) fadd(a[k], b[k], c, r[k], c);
    r[5] = c;
}
__device__ __forceinline__ void add6(const uint32_t* a, const uint32_t* b, uint32_t* r) {
    uint32_t c;
    hadd(a[0], b[0], r[0], c);
#pragma unroll
    for (int k = 1; k < 6; ++k) fadd(a[k], b[k], c, r[k], c);
    r[6] = c;
}

// grid: blocks 0..511 = (b,y) SWAR interior (y borders skip); 512..639 = y-border path.
__global__ __launch_bounds__(256) void core_kernel(const uint32_t* __restrict__ xbits,
                                                   const uint32_t* __restrict__ winv,
                                                   float* __restrict__ out) {
    __shared__ uint32_t wlds[CI * CO];       // 16 KiB
    __shared__ uint4 xr4[CI];                // rows y-1,y,y+1
    __shared__ uint32_t red[4][CO][5];       // per-ciq 5 bit-planes
    __shared__ uint32_t planes7[CO][7];      // reduced 7 bit-planes
    __shared__ int bord[CO][2][2];           // x-border partial sums

    const int bid = blockIdx.x;
    const int tid = threadIdx.x;

    if (bid < BB * HH) {
        const int b = bid >> 5, y = bid & 31;
        if (y == 0 || y == HH - 1) return;   // whole block exits before any barrier

        {   // stage winv (coalesced) + 3 x-rows
            const uint4* src = (const uint4*)winv;
            uint4* dst = (uint4*)wlds;
#pragma unroll
            for (int i = 0; i < 4; ++i) dst[tid + i * 256] = src[tid + i * 256];
        }
        if (tid < 3 * CI) {
            int r = tid >> 6, ci = tid & 63;
            ((uint32_t*)&xr4[ci])[r] = xbits[(b * CI + ci) * HH + (y - 1 + r)];
        }
        __syncthreads();

        const int co = tid & 63, ciq = tid >> 6;

        // ---- SWAR majority-of-9 over 32 pixels, 16 ci per thread ----
        uint32_t maj[16];
#pragma unroll
        for (int i = 0; i < 16; ++i) {
            const int ci = ciq * 16 + i;
            const uint4 xr = xr4[ci];
            const uint32_t wn = wlds[ci * CO + co];
            const uint32_t T0 = xr.x << 1, T1 = xr.x, T2 = xr.x >> 1;
            const uint32_t T3 = xr.y << 1, T4 = xr.y, T5 = xr.y >> 1;
            const uint32_t T6 = xr.z << 1, T7 = xr.z, T8 = xr.z >> 1;
            const uint32_t m0 = T0 ^ (uint32_t)(-(int)((wn >> 0) & 1));
            const uint32_t m1 = T1 ^ (uint32_t)(-(int)((wn >> 1) & 1));
            const uint32_t m2 = T2 ^ (uint32_t)(-(int)((wn >> 2) & 1));
            const uint32_t m3 = T3 ^ (uint32_t)(-(int)((wn >> 3) & 1));
            const uint32_t m4 = T4 ^ (uint32_t)(-(int)((wn >> 4) & 1));
            const uint32_t m5 = T5 ^ (uint32_t)(-(int)((wn >> 5) & 1));
            const uint32_t m6 = T6 ^ (uint32_t)(-(int)((wn >> 6) & 1));
            const uint32_t m7 = T7 ^ (uint32_t)(-(int)((wn >> 7) & 1));
            const uint32_t m8 = T8 ^ (uint32_t)(-(int)((wn >> 8) & 1));
            uint32_t s1, c1, s2, c2, s3, c3, S, C, D, E;
            fadd(m0, m1, m2, s1, c1);
            fadd(m3, m4, m5, s2, c2);
            fadd(m6, m7, m8, s3, c3);
            fadd(s1, s2, s3, S, C);              // m = S + 2C + 2D + 4E
            fadd(c1, c2, c3, D, E);
            maj[i] = (E & (S | C | D)) | (~E & (S & C & D));   // m >= 5
        }

        // ---- CSA: 16 maj bits -> 5 planes (count 0..16) ----
        uint32_t A[5], Bw[5];
        fadd(maj[0], maj[1], maj[2], A[0], Bw[0]);
        fadd(maj[3], maj[4], maj[5], A[1], Bw[1]);
        fadd(maj[6], maj[7], maj[8], A[2], Bw[2]);
        fadd(maj[9], maj[10], maj[11], A[3], Bw[3]);
        fadd(maj[12], maj[13], maj[14], A[4], Bw[4]);
        uint32_t u1, v1, u2, v2, p0, v3;
        fadd(A[0], A[1], A[2], u1, v1);
        fadd(A[3], A[4], maj[15], u2, v2);
        hadd(u1, u2, p0, v3);
        uint32_t e1, f1, e2, f2, e3, f3, p1, f4;
        fadd(Bw[0], Bw[1], Bw[2], e1, f1);
        fadd(Bw[3], Bw[4], v1, e2, f2);
        fadd(e1, e2, v2, e3, f3);
        hadd(e3, v3, p1, f4);
        uint32_t g1, h1, p2, h2, p3, p4;
        fadd(f1, f2, f3, g1, h1);
        hadd(g1, f4, p2, h2);
        hadd(h1, h2, p3, p4);
        red[ciq][co][0] = p0; red[ciq][co][1] = p1; red[ciq][co][2] = p2;
        red[ciq][co][3] = p3; red[ciq][co][4] = p4;

        // ---- x-border scalar fixup: px 0 and 31 (N=6), 32 ci per thread ----
        {
            const int fco = tid & 63, side = (tid >> 6) & 1, cih = tid >> 7;
            const int px = side * (WW - 1);
            const uint32_t rowm = (px > 0 ? 1u : 0u) | 2u | (px < WW - 1 ? 4u : 0u);
            const uint32_t vmask = rowm | (rowm << 3) | (rowm << 6);   // y interior
            const uint32_t nt1 = __popc(vmask) >> 1, nt2 = (__popc(vmask) - 1) >> 1;
            uint32_t lut = 0;
            for (uint32_t m = 1; m <= 9; ++m)
                lut |= (uint32_t)((m > nt1) + (m > nt2)) << (2 * m);
            int acc = 0;
            for (int i = 0; i < 32; ++i) {
                const int ci = cih * 32 + i;
                const uint4 xr = xr4[ci];
                const uint32_t wn = wlds[ci * CO + fco];
                const uint32_t n0 = (uint32_t)((((uint64_t)xr.x) << 1) >> px) & 7u;
                const uint32_t n1 = (uint32_t)((((uint64_t)xr.y) << 1) >> px) & 7u;
                const uint32_t n2 = (uint32_t)((((uint64_t)xr.z) << 1) >> px) & 7u;
                const uint32_t xn = n0 | (n1 << 3) | (n2 << 6);
                const uint32_t mm = (uint32_t)__popc((xn ^ wn) & vmask);  // matches
                acc += (lut >> (2 * mm)) & 3u;
            }
            bord[fco][side][cih] = acc;
        }
        __syncthreads();

        // ---- reduce 4 ciq counts -> 7 planes per co (wave 0 only) ----
        if (tid < 64) {
            uint32_t x0[6], x1[6], rr[7];
            add5(red[0][tid], red[1][tid], x0);
            add5(red[2][tid], red[3][tid], x1);
            add6(x0, x1, rr);
#pragma unroll
            for (int k = 0; k < 7; ++k) planes7[tid][k] = rr[k];
        }
        __syncthreads();

        // ---- extract + store: thread (co,q) -> px q*8..q*8+7 ----
        {
            const int oco = tid & 63, q = tid >> 6;
            uint32_t pl[7];
#pragma unroll
            for (int k = 0; k < 7; ++k) pl[k] = planes7[oco][k];
            float vals[8];
#pragma unroll
            for (int j = 0; j < 8; ++j) {
                const int px = q * 8 + j;
                uint32_t cnt = 0;
#pragma unroll
                for (int k = 0; k < 7; ++k) cnt += ((pl[k] >> px) & 1u) << k;
                vals[j] = (float)(2 * (int)cnt - CI);   // interior: sign = 2*maj-1
            }
            if (q == 0) vals[0] = (float)(bord[oco][0][0] + bord[oco][0][1] - CI);
            if (q == 3) vals[7] = (float)(bord[oco][1][0] + bord[oco][1][1] - CI);
            float4* op = (float4*)&out[((size_t)(b * CO + oco) * HH + y) * WW + q * 8];
            op[0] = make_float4(vals[0], vals[1], vals[2], vals[3]);
            op[1] = make_float4(vals[4], vals[5], vals[6], vals[7]);
        }
    } else {
        // ---- y-border rows (y=0,31): generic-LUT scalar, 2 co per thread ----
        const int idx = bid - BB * HH;            // 0..127
        const int b = idx >> 3, yb = (idx >> 2) & 1, coq = idx & 3;
        const int y = yb * (HH - 1);
        for (int i = tid; i < CI * 16; i += 256) {  // winv subset [ci][16 co]
            int ci = i >> 4, c = i & 15;
            wlds[i] = winv[ci * CO + coq * 16 + c];
        }
        if (tid < 3 * CI) {
            int r = tid >> 6, ci = tid & 63;
            int yy = y - 1 + r;
            ((uint32_t*)&xr4[ci])[r] = (yy >= 0 && yy < HH) ? xbits[(b * CI + ci) * HH + yy] : 0u;
        }
        __syncthreads();

        const int px = tid & 31, cog = tid >> 5;   // 2 co each
        const uint32_t rowm = (px > 0 ? 1u : 0u) | 2u | (px < WW - 1 ? 4u : 0u);
        const uint32_t vmask = (y > 0 ? rowm : 0u) | (rowm << 3) |
                               (y < HH - 1 ? (rowm << 6) : 0u);
        const uint32_t N = __popc(vmask);
        const uint32_t nt1 = N >> 1, nt2 = (N - 1) >> 1;
        uint32_t lut = 0;
        for (uint32_t m = 1; m <= 9; ++m)
            lut |= (uint32_t)((m > nt1) + (m > nt2)) << (2 * m);
        int a0 = 0, a1 = 0;
        for (int ci = 0; ci < CI; ++ci) {
            const uint4 xr = xr4[ci];
            const uint32_t n0 = (uint32_t)((((uint64_t)xr.x) << 1) >> px) & 7u;
            const uint32_t n1 = (uint32_t)((((uint64_t)xr.y) << 1) >> px) & 7u;
            const uint32_t n2 = (uint32_t)((((uint64_t)xr.z) << 1) >> px) & 7u;
            const uint32_t xn = n0 | (n1 << 3) | (n2 << 6);
            const uint32_t w0 = wlds[ci * 16 + cog * 2 + 0];
            const uint32_t w1 = wlds[ci * 16 + cog * 2 + 1];
            uint32_t mm;
            mm = (uint32_t)__popc((xn ^ w0) & vmask); a0 += (lut >> (2 * mm)) & 3u;
            mm = (uint32_t)__popc((xn ^ w1) & vmask); a1 += (lut >> (2 * mm)) & 3u;
        }
        const int co0 = coq * 16 + cog * 2;
        out[((size_t)(b * CO + co0 + 0) * HH + y) * WW + px] = (float)(a0 - CI);
        out[((size_t)(b * CO + co0 + 1) * HH + y) * WW + px] = (float)(a1 - CI);
    }
}

extern "C" void kernel_launch(void* const* d_in, const int* in_sizes, int n_in,
                              void* d_out, int out_size, void* d_ws, size_t ws_size,
                              hipStream_t stream) {
    const float* x = (const float*)d_in[0];
    const float* w = (const float*)d_in[1];
    float* out = (float*)d_out;

    uint32_t* xbits = (uint32_t*)d_ws;          // 16384 words
    uint32_t* winv = xbits + BB * CI * HH;      // 4096 words

    const int XBLK = (BB * CI * HH * WW) / 256; // 4096
    pack_kernel<<<XBLK + 16, 256, 0, stream>>>(x, w, xbits, winv);
    core_kernel<<<BB * HH + 128, 256, 0, stream>>>(xbits, winv, out);
}